// Round 11
// baseline (105.637 us; speedup 1.0000x reference)
//
#include <hip/hip_runtime.h>
#include <hip/hip_bf16.h>
#include <math.h>

#define B_ 2
#define S_ 2048
#define D_ 1024
#define H_ 16
#define G_ 4
#define HD_ 64

typedef float f32x4  __attribute__((ext_vector_type(4)));
typedef float f32x16 __attribute__((ext_vector_type(16)));
typedef short s16x8  __attribute__((ext_vector_type(8)));
typedef unsigned short u16x4 __attribute__((ext_vector_type(4)));
typedef unsigned int   u32x4 __attribute__((ext_vector_type(4)));

__device__ __forceinline__ unsigned short f2b(float f) {
    __hip_bfloat16 h = __float2bfloat16(f);
    return __builtin_bit_cast(unsigned short, h);
}
__device__ __forceinline__ float b2f(unsigned short u) {
    return __builtin_bit_cast(float, (unsigned)u << 16);
}
__device__ __forceinline__ unsigned cvtpk(float lo, float hi) {
    unsigned r;
    asm("v_cvt_pk_bf16_f32 %0, %1, %2" : "=v"(r) : "v"(lo), "v"(hi));
    return r;
}
__device__ __forceinline__ void plswap(unsigned &a, unsigned &b) {
    asm("v_permlane32_swap_b32 %0, %1" : "+v"(a), "+v"(b));
}

#define MFMA16(a, b, c) __builtin_amdgcn_mfma_f32_16x16x32_bf16(a, b, c, 0, 0, 0)
#define MFMA32(a, b, c) __builtin_amdgcn_mfma_f32_32x32x16_bf16(a, b, c, 0, 0, 0)

#define GLOAD16(gp, lp) __builtin_amdgcn_global_load_lds(                      \
    (const __attribute__((address_space(1))) void*)(gp),                      \
    (__attribute__((address_space(3))) void*)(lp), 16, 0, 0)

// ---------------- prep: bf16 casts + pooled K/V weights + rope tables -------
__global__ __launch_bounds__(256)
void prep_all(const float* __restrict__ x,  const float* __restrict__ Wq,
              const float* __restrict__ Wk, const float* __restrict__ Wv,
              const float* __restrict__ Wo,
              unsigned short* __restrict__ xb, unsigned short* __restrict__ wb,
              unsigned short* __restrict__ wob,
              float* __restrict__ cost, float* __restrict__ sint)
{
    const int NQ_WB = (1536*1024)/4;
    const int NQ_WO = (1024*1024)/4;
    const int NQ_X  = (B_*S_*D_)/4;
    int q = blockIdx.x*256 + threadIdx.x;
    if (q < NQ_WB) {
        const int idx = q*4, row = idx >> 10, c = idx & 1023;
        u16x4 o;
        if (row < 1024) {
            f32x4 v = *(const f32x4*)&Wq[(size_t)row*1024 + c];
            #pragma unroll
            for (int j = 0; j < 4; ++j) o[j] = f2b(v[j]);
        } else {
            const int rd = row - 1024, kv = rd >> 8, gd = rd & 255;
            const int g = gd >> 6, d = gd & 63;
            const float* W = kv ? Wv : Wk;
            f32x4 sum = {0.f, 0.f, 0.f, 0.f};
            #pragma unroll
            for (int p = 0; p < 4; ++p)
                sum += *(const f32x4*)&W[(size_t)((g*4 + p)*64 + d)*1024 + c];
            #pragma unroll
            for (int j = 0; j < 4; ++j) o[j] = f2b(sum[j]*0.25f);
        }
        *(u16x4*)&wb[idx] = o;
        return;
    }
    q -= NQ_WB;
    if (q < NQ_WO) {
        const int idx = q*4;
        f32x4 v = *(const f32x4*)&Wo[idx];
        u16x4 o;
        #pragma unroll
        for (int j = 0; j < 4; ++j) o[j] = f2b(v[j]);
        *(u16x4*)&wob[idx] = o;
        return;
    }
    q -= NQ_WO;
    if (q < NQ_X) {
        const int idx = q*4;
        f32x4 v = *(const f32x4*)&x[idx];
        u16x4 o;
        #pragma unroll
        for (int j = 0; j < 4; ++j) o[j] = f2b(v[j]);
        *(u16x4*)&xb[idx] = o;
        return;
    }
    q -= NQ_X;
    if (q < (S_*32)/4) {
        const int idx = q*4, s = idx >> 5, f0 = idx & 31;
        #pragma unroll
        for (int j = 0; j < 4; ++j) {
            const float f = (float)(f0 + j);
            const float fr = (float)s * powf(10000.0f, -f*(1.0f/32.0f));
            cost[idx + j] = cosf(fr);
            sint[idx + j] = sinf(fr);
        }
    }
}

// ---------------- MFMA GEMM: C = A(Mx1024) * B(Nx1024)^T, 128x128 tile ------
// MODE 0: fused QKV epilogue (bx<8: Q rope+permute+*C; bx<10: K rope; else V^T)
// MODE 1: fp32 store (O-projection)
template<int MODE>
__global__ __launch_bounds__(256)
void gemm_mfma(const unsigned short* __restrict__ Am,
               const unsigned short* __restrict__ Bm,
               unsigned short* __restrict__ qr,
               unsigned short* __restrict__ kr,
               unsigned short* __restrict__ vt,
               float* __restrict__ outf,
               const float* __restrict__ cost,
               const float* __restrict__ sint,
               int nbx)
{
    __shared__ unsigned short As[2][128*64];
    __shared__ unsigned short Bs[2][128*64];

    const int nwg = gridDim.x;
    const int cpx = nwg >> 3;
    const int bid = blockIdx.x;
    const int swz = (bid & 7)*cpx + (bid >> 3);     // XCD-chunked (bijective)
    const int bx = swz % nbx, by = swz / nbx;

    const int t  = threadIdx.x;
    const int w  = t >> 6, l = t & 63;
    const int lg = l >> 4, lr = l & 15;
    const int wr = w >> 1, wc = w & 1;

    const unsigned short* gA = Am + (size_t)by*128*D_;
    const unsigned short* gB = Bm + (size_t)bx*128*D_;

    const int srow = l >> 3;
    const int schk = (l & 7) ^ srow;

#define STAGE(buf, k0)                                                         \
    _Pragma("unroll")                                                          \
    for (int i_ = 0; i_ < 4; ++i_) {                                           \
        const int row_ = 32*w + 8*i_ + srow;                                   \
        GLOAD16(gA + (size_t)row_*D_ + (k0) + 8*schk, &As[buf][(32*w + 8*i_)*64]); \
        GLOAD16(gB + (size_t)row_*D_ + (k0) + 8*schk, &Bs[buf][(32*w + 8*i_)*64]); \
    }

    f32x4 acc[4][4] = {};

    STAGE(0, 0);
    #pragma unroll 1
    for (int kt = 0; kt < 16; ++kt) {
        const int cur = kt & 1;
        if (kt < 15) {
            STAGE(cur ^ 1, 64*(kt + 1));
            asm volatile("s_waitcnt vmcnt(8)" ::: "memory");
        } else {
            asm volatile("s_waitcnt vmcnt(0)" ::: "memory");
        }
        __builtin_amdgcn_s_barrier();

        #pragma unroll
        for (int kk = 0; kk < 2; ++kk) {
            s16x8 af[4], bfr[4];
            #pragma unroll
            for (int m = 0; m < 4; ++m) {
                const int row = 64*wr + 16*m + lr;
                af[m] = *(const s16x8*)&As[cur][row*64 + 8*((lg + 4*kk) ^ (row & 7))];
            }
            #pragma unroll
            for (int n = 0; n < 4; ++n) {
                const int col = 64*wc + 16*n + lr;
                bfr[n] = *(const s16x8*)&Bs[cur][col*64 + 8*((lg + 4*kk) ^ (col & 7))];
            }
            #pragma unroll
            for (int m = 0; m < 4; ++m)
                #pragma unroll
                for (int n = 0; n < 4; ++n)
                    acc[m][n] = MFMA16(af[m], bfr[n], acc[m][n]);
        }
        asm volatile("s_waitcnt lgkmcnt(0)" ::: "memory");
        __builtin_amdgcn_s_barrier();
    }
#undef STAGE

    if (MODE == 1) {
        #pragma unroll
        for (int m = 0; m < 4; ++m)
            #pragma unroll
            for (int r = 0; r < 4; ++r) {
                const int row = by*128 + 64*wr + 16*m + 4*lg + r;
                #pragma unroll
                for (int n = 0; n < 4; ++n)
                    outf[(size_t)row*D_ + bx*128 + 64*wc + 16*n + lr] = acc[m][n][r];
            }
        return;
    }

    if (bx < 10) {   // Q (bx<8) or K (bx 8,9): rope; partner dd^32 = acc[m][n^2]
        const float CQ = 0.18033688011112044f;   // (1/8)*log2(e), folded into Q
        #pragma unroll
        for (int m = 0; m < 4; ++m) {
            #pragma unroll
            for (int r = 0; r < 4; ++r) {
                const int row = by*128 + 64*wr + 16*m + 4*lg + r;
                const int b = row >> 11, s = row & (S_ - 1);
                const float c_lo = cost[s*32 + lr],      s_lo = sint[s*32 + lr];
                const float c_hi = cost[s*32 + 16 + lr], s_hi = sint[s*32 + 16 + lr];
                unsigned short vals[4];
                #pragma unroll
                for (int n = 0; n < 4; ++n) {
                    const float cc = (n & 1) ? c_hi : c_lo;
                    const float sn = (n & 1) ? s_hi : s_lo;
                    const float self = acc[m][n][r], part = acc[m][n ^ 2][r];
                    float rv = (n < 2) ? fmaf(self, cc, -part*sn)
                                       : fmaf(self, cc,  part*sn);
                    if (bx < 8) rv *= CQ;
                    vals[n] = f2b(rv);
                }
                size_t base;
                unsigned short* dst;
                if (bx < 8) {
                    const int hh = 2*bx + wc;
                    const int hp = (hh & 3)*4 + (hh >> 2);  // swapaxes(2,3)
                    base = (((size_t)b*H_ + hp)*S_ + s)*HD_;
                    dst = qr;
                } else {
                    const int g = (bx - 8)*2 + wc;
                    base = (((size_t)b*G_ + g)*S_ + s)*HD_;
                    dst = kr;
                }
                #pragma unroll
                for (int n = 0; n < 4; ++n) dst[base + 16*n + lr] = vals[n];
            }
        }
    } else {         // V: store transposed vt[b][g][dd][s]
        const int g = (bx - 10)*2 + wc;
        #pragma unroll
        for (int m = 0; m < 4; ++m) {
            const int row0 = by*128 + 64*wr + 16*m + 4*lg;
            const int b = row0 >> 11, s0 = row0 & (S_ - 1);
            #pragma unroll
            for (int n = 0; n < 4; ++n) {
                const int dd = 16*n + lr;
                u16x4 v;
                #pragma unroll
                for (int r = 0; r < 4; ++r) v[r] = f2b(acc[m][n][r]);
                *(u16x4*)&vt[(((size_t)b*G_ + g)*HD_ + dd)*S_ + s0] = v;
            }
        }
    }
}

// ---------------- MFMA flash attention, split-K2, max-free softmax ----------
// Grid = B*H*(S/128)*2 halves = 1024 blocks -> 4 blocks/CU -> 4 waves/SIMD.
// Each block: 4 waves x 32 q-rows, 1024 keys, KVBLK=64 dbuf (32 KB LDS).
// Max-free (Q pre-scaled by (1/8)*log2e, scores bounded); l via ones-MFMA.
// Partials: po bf16 (undivided o), pl f32; combined by combine_kernel.
__device__ __forceinline__ void stage64(const unsigned short* Kp, const unsigned short* Vp,
                                        unsigned short* ks, unsigned short* vs,
                                        int key0, int w, int l)
{
    const int srow = l >> 3;            // 0..7
    const int schk = (l & 7) ^ srow;    // pre-swizzled 16B chunk
    #pragma unroll
    for (int i = 0; i < 2; ++i) {
        const int row = 16*w + 8*i + srow;                 // row & 7 == srow
        GLOAD16(Kp + ((size_t)(key0 + row))*HD_ + 8*schk, ks + (16*w + 8*i)*64);
        GLOAD16(Vp + (size_t)row*S_ + key0 + 8*schk,      vs + (16*w + 8*i)*64);
    }
}

__global__ __launch_bounds__(256, 4)
void flash_attn_mfma(const unsigned short* __restrict__ qr,
                     const unsigned short* __restrict__ kr,
                     const unsigned short* __restrict__ vt,
                     unsigned short* __restrict__ po,
                     float* __restrict__ pl)
{
    __shared__ unsigned short Ks[2][64*64];
    __shared__ unsigned short Vs[2][64*64];

    const int bid  = blockIdx.x;
    const int cpx  = gridDim.x >> 3;
    const int swz  = (bid & 7)*cpx + (bid >> 3);   // XCD-chunked
    const int qt   = swz & 15;
    const int h    = (swz >> 4) & 15;
    const int b    = (swz >> 8) & 1;
    const int half = swz >> 9;
    const int g    = h >> 2;
    const int t    = threadIdx.x;
    const int w    = t >> 6;
    const int l    = t & 63;
    const int hi   = l >> 5;
    const int li   = l & 31;

    const unsigned short* Qp = qr + (((size_t)b*H_ + h)*S_ + (size_t)qt*128 + w*32)*HD_;
    const unsigned short* Kp = kr + ((size_t)b*G_ + g)*(size_t)S_*HD_ + (size_t)half*1024*HD_;
    const unsigned short* Vp = vt + ((size_t)b*G_ + g)*(size_t)HD_*S_ + half*1024;

    s16x8 qf[4];
    #pragma unroll
    for (int kk = 0; kk < 4; ++kk)
        qf[kk] = *(const s16x8*)(Qp + (size_t)li*HD_ + 16*kk + 8*hi);

    s16x8 ones;
    #pragma unroll
    for (int e = 0; e < 8; ++e) ones[e] = (short)0x3F80;   // bf16 1.0

    f32x16 o[2], o_l;
    #pragma unroll
    for (int e = 0; e < 16; ++e) { o[0][e] = 0.f; o[1][e] = 0.f; o_l[e] = 0.f; }

    const int NT = 1024/64;   // 16 phases over this block's key half
    stage64(Kp, Vp, Ks[0], Vs[0], 0, w, l);

    #pragma unroll 1
    for (int kt = 0; kt < NT; ++kt) {
        const int cur = kt & 1;
        if (kt + 1 < NT) {
            stage64(Kp, Vp, Ks[cur^1], Vs[cur^1], 64*(kt + 1), w, l);
            asm volatile("s_waitcnt vmcnt(4)" ::: "memory");
        } else {
            asm volatile("s_waitcnt vmcnt(0)" ::: "memory");
        }
        __builtin_amdgcn_s_barrier();

        // ---- QK^T: 64 keys = 2 x 32-key subtiles, independent chains ----
        f32x16 sc[2];
        #pragma unroll
        for (int q4 = 0; q4 < 2; ++q4)
            #pragma unroll
            for (int e = 0; e < 16; ++e) sc[q4][e] = 0.f;

        __builtin_amdgcn_s_setprio(1);
        #pragma unroll
        for (int kk = 0; kk < 4; ++kk) {
            const int chk = 8*((hi + 2*kk) ^ (li & 7));
            #pragma unroll
            for (int q4 = 0; q4 < 2; ++q4) {
                s16x8 kf = *(const s16x8*)&Ks[cur][(32*q4 + li)*64 + chk];
                sc[q4] = MFMA32(kf, qf[kk], sc[q4]);
            }
        }
        __builtin_amdgcn_s_setprio(0);

        // ---- P = exp2(sc), 32 batched transcendentals ----
        #pragma unroll
        for (int q4 = 0; q4 < 2; ++q4)
            #pragma unroll
            for (int e = 0; e < 16; ++e)
                sc[q4][e] = __builtin_amdgcn_exp2f(sc[q4][e]);

        // ---- pack (cvt_pk + permlane32_swap) + PV + l-via-MFMA ----
        __builtin_amdgcn_s_setprio(1);
        #pragma unroll
        for (int q4 = 0; q4 < 2; ++q4) {
            #pragma unroll
            for (int s2 = 0; s2 < 2; ++s2) {
                unsigned a0 = cvtpk(sc[q4][8*s2+0], sc[q4][8*s2+1]);
                unsigned a1 = cvtpk(sc[q4][8*s2+2], sc[q4][8*s2+3]);
                unsigned a2 = cvtpk(sc[q4][8*s2+4], sc[q4][8*s2+5]);
                unsigned a3 = cvtpk(sc[q4][8*s2+6], sc[q4][8*s2+7]);
                plswap(a0, a2); plswap(a1, a3);
                u32x4 aw = {a0, a1, a2, a3};
                s16x8 paf = __builtin_bit_cast(s16x8, aw);
                const int ks = 2*q4 + s2;            // 16-key slice in tile
                #pragma unroll
                for (int dt = 0; dt < 2; ++dt) {
                    const int d = li + 32*dt;
                    s16x8 vf = *(const s16x8*)&Vs[cur][d*64 + 8*((hi + 2*ks) ^ (li & 7))];
                    o[dt] = MFMA32(paf, vf, o[dt]);
                }
                o_l = MFMA32(paf, ones, o_l);        // row-sum on matrix pipe
            }
        }
        __builtin_amdgcn_s_setprio(0);

        asm volatile("s_waitcnt lgkmcnt(0)" ::: "memory");
        __builtin_amdgcn_s_barrier();
    }

    // ---- epilogue: write UNDIVIDED partials (combine kernel divides) -------
    const size_t pbase = (((size_t)half*B_ + b)*H_ + h)*S_;
    #pragma unroll
    for (int r = 0; r < 16; ++r) {
        const int qq = (r & 3) + 8*(r >> 2) + 4*hi;
        const int s  = qt*128 + w*32 + qq;
        #pragma unroll
        for (int dt = 0; dt < 2; ++dt)
            po[(pbase + s)*HD_ + li + 32*dt] = f2b(o[dt][r]);
        if (li == 0) pl[pbase + s] = o_l[r];
    }
}

// ---------------- combine: attnb = (o0+o1)/(l0+l1) --------------------------
__global__ __launch_bounds__(256)
void combine_kernel(const unsigned short* __restrict__ po,
                    const float* __restrict__ pl,
                    unsigned short* __restrict__ attnb)
{
    const int i  = blockIdx.x*256 + threadIdx.x;     // B*H*S*HD/8 = 524288
    const int d8 = i & 7;
    const int s  = (i >> 3) & (S_ - 1);
    const int h  = (i >> 14) & (H_ - 1);
    const int b  = i >> 18;
    const size_t r0 = (((size_t)b)*H_ + h)*S_ + s;
    const size_t r1 = (((size_t)B_ + b)*H_ + h)*S_ + s;
    const float inv = 1.0f / (pl[r0] + pl[r1]);
    s16x8 p0 = *(const s16x8*)&po[r0*HD_ + d8*8];
    s16x8 p1 = *(const s16x8*)&po[r1*HD_ + d8*8];
    s16x8 ov;
    #pragma unroll
    for (int j = 0; j < 8; ++j) {
        const float v = (b2f((unsigned short)p0[j]) + b2f((unsigned short)p1[j])) * inv;
        ov[j] = (short)f2b(v);
    }
    *(s16x8*)&attnb[((size_t)b*S_ + s)*D_ + h*HD_ + d8*8] = ov;
}

extern "C" void kernel_launch(void* const* d_in, const int* in_sizes, int n_in,
                              void* d_out, int out_size, void* d_ws, size_t ws_size,
                              hipStream_t stream)
{
    const float* x  = (const float*)d_in[0];
    const float* Wq = (const float*)d_in[1];
    const float* Wk = (const float*)d_in[2];
    const float* Wv = (const float*)d_in[3];
    const float* Wo = (const float*)d_in[4];
    float* out = (float*)d_out;

    // Workspace (~39 MB): po aliases the xb+wb region (dead after QKV GEMM).
    char* p = (char*)d_ws;
    unsigned short* qr    = (unsigned short*)p; p += (size_t)B_*H_*S_*HD_*2;   // 8 MB
    unsigned short* kr    = (unsigned short*)p; p += (size_t)B_*G_*S_*HD_*2;   // 2 MB
    unsigned short* vt    = (unsigned short*)p; p += (size_t)B_*G_*HD_*S_*2;   // 2 MB
    unsigned short* wob   = (unsigned short*)p; p += (size_t)1024*1024*2;      // 2 MB
    unsigned short* attnb = (unsigned short*)p; p += (size_t)B_*S_*D_*2;       // 8 MB
    float* pl   = (float*)p;  p += (size_t)2*B_*H_*S_*4;                       // 0.5 MB
    float* cost = (float*)p;  p += (size_t)S_*32*4;
    float* sint = (float*)p;  p += (size_t)S_*32*4;
    char* regionX = p;                                                         // 16 MB
    unsigned short* xb = (unsigned short*)regionX;                 // dead after QKV
    unsigned short* wb = (unsigned short*)(regionX + (size_t)B_*S_*D_*2);
    unsigned short* po = (unsigned short*)regionX;                 // reuses xb/wb

    prep_all<<<6720, 256, 0, stream>>>(x, Wq, Wk, Wv, Wo, xb, wb, wob, cost, sint);
    gemm_mfma<0><<<32*12, 256, 0, stream>>>(xb, wb, qr, kr, vt, nullptr, cost, sint, 12);
    flash_attn_mfma<<<B_*H_*(S_/128)*2, 256, 0, stream>>>(qr, kr, vt, po, pl);
    combine_kernel<<<(B_*H_*S_*HD_/8)/256, 256, 0, stream>>>(po, pl, attnb);
    gemm_mfma<1><<<32*8, 256, 0, stream>>>(attnb, wob, nullptr, nullptr, nullptr, out, cost, sint, 8);
}

// Round 12
// 99.127 us; speedup vs baseline: 1.0657x; 1.0657x over previous
//
#include <hip/hip_runtime.h>
#include <hip/hip_bf16.h>
#include <math.h>

#define B_ 2
#define S_ 2048
#define D_ 1024
#define H_ 16
#define G_ 4
#define HD_ 64

typedef float f32x4  __attribute__((ext_vector_type(4)));
typedef float f32x16 __attribute__((ext_vector_type(16)));
typedef short s16x8  __attribute__((ext_vector_type(8)));
typedef unsigned short u16x4 __attribute__((ext_vector_type(4)));
typedef unsigned int   u32x4 __attribute__((ext_vector_type(4)));

__device__ __forceinline__ unsigned short f2b(float f) {
    __hip_bfloat16 h = __float2bfloat16(f);
    return __builtin_bit_cast(unsigned short, h);
}
__device__ __forceinline__ unsigned cvtpk(float lo, float hi) {
    unsigned r;
    asm("v_cvt_pk_bf16_f32 %0, %1, %2" : "=v"(r) : "v"(lo), "v"(hi));
    return r;
}
__device__ __forceinline__ void plswap(unsigned &a, unsigned &b) {
    asm("v_permlane32_swap_b32 %0, %1" : "+v"(a), "+v"(b));
}

#define MFMA16(a, b, c) __builtin_amdgcn_mfma_f32_16x16x32_bf16(a, b, c, 0, 0, 0)
#define MFMA32(a, b, c) __builtin_amdgcn_mfma_f32_32x32x16_bf16(a, b, c, 0, 0, 0)

#define GLOAD16(gp, lp) __builtin_amdgcn_global_load_lds(                      \
    (const __attribute__((address_space(1))) void*)(gp),                      \
    (__attribute__((address_space(3))) void*)(lp), 16, 0, 0)

// ---------------- prep: bf16 casts + pooled K/V weights + rope tables -------
__global__ __launch_bounds__(256)
void prep_all(const float* __restrict__ x,  const float* __restrict__ Wq,
              const float* __restrict__ Wk, const float* __restrict__ Wv,
              const float* __restrict__ Wo,
              unsigned short* __restrict__ xb, unsigned short* __restrict__ wb,
              unsigned short* __restrict__ wob,
              float* __restrict__ cost, float* __restrict__ sint)
{
    const int NQ_WB = (1536*1024)/4;
    const int NQ_WO = (1024*1024)/4;
    const int NQ_X  = (B_*S_*D_)/4;
    int q = blockIdx.x*256 + threadIdx.x;
    if (q < NQ_WB) {
        const int idx = q*4, row = idx >> 10, c = idx & 1023;
        u16x4 o;
        if (row < 1024) {
            f32x4 v = *(const f32x4*)&Wq[(size_t)row*1024 + c];
            #pragma unroll
            for (int j = 0; j < 4; ++j) o[j] = f2b(v[j]);
        } else {
            const int rd = row - 1024, kv = rd >> 8, gd = rd & 255;
            const int g = gd >> 6, d = gd & 63;
            const float* W = kv ? Wv : Wk;
            f32x4 sum = {0.f, 0.f, 0.f, 0.f};
            #pragma unroll
            for (int p = 0; p < 4; ++p)
                sum += *(const f32x4*)&W[(size_t)((g*4 + p)*64 + d)*1024 + c];
            #pragma unroll
            for (int j = 0; j < 4; ++j) o[j] = f2b(sum[j]*0.25f);
        }
        *(u16x4*)&wb[idx] = o;
        return;
    }
    q -= NQ_WB;
    if (q < NQ_WO) {
        const int idx = q*4;
        f32x4 v = *(const f32x4*)&Wo[idx];
        u16x4 o;
        #pragma unroll
        for (int j = 0; j < 4; ++j) o[j] = f2b(v[j]);
        *(u16x4*)&wob[idx] = o;
        return;
    }
    q -= NQ_WO;
    if (q < NQ_X) {
        const int idx = q*4;
        f32x4 v = *(const f32x4*)&x[idx];
        u16x4 o;
        #pragma unroll
        for (int j = 0; j < 4; ++j) o[j] = f2b(v[j]);
        *(u16x4*)&xb[idx] = o;
        return;
    }
    q -= NQ_X;
    if (q < (S_*32)/4) {
        const int idx = q*4, s = idx >> 5, f0 = idx & 31;
        #pragma unroll
        for (int j = 0; j < 4; ++j) {
            const float f = (float)(f0 + j);
            const float fr = (float)s * powf(10000.0f, -f*(1.0f/32.0f));
            cost[idx + j] = cosf(fr);
            sint[idx + j] = sinf(fr);
        }
    }
}

// ---------------- MFMA GEMM: C = A(Mx1024) * B(Nx1024)^T, 64x128 tile -------
// BM=64 for occupancy (QKV: 768 blocks = 3/CU, O-proj: 512 = 2/CU; 48KB LDS).
// 4 waves as 2x2 -> each wave 32 rows x 64 cols = acc[2][4].
// MODE 0: fused QKV epilogue (bx<8: Q rope+permute+*C; bx<10: K rope; else V^T)
// MODE 1: fp32 store (O-projection)
template<int MODE>
__global__ __launch_bounds__(256)
void gemm_mfma(const unsigned short* __restrict__ Am,
               const unsigned short* __restrict__ Bm,
               unsigned short* __restrict__ qr,
               unsigned short* __restrict__ kr,
               unsigned short* __restrict__ vt,
               float* __restrict__ outf,
               const float* __restrict__ cost,
               const float* __restrict__ sint,
               int nbx)
{
    __shared__ unsigned short As[2][64*64];    // 16 KB
    __shared__ unsigned short Bs[2][128*64];   // 32 KB

    const int nwg = gridDim.x;
    const int cpx = nwg >> 3;
    const int bid = blockIdx.x;
    const int swz = (bid & 7)*cpx + (bid >> 3);     // XCD-chunked (bijective)
    const int bx = swz % nbx, by = swz / nbx;

    const int t  = threadIdx.x;
    const int w  = t >> 6, l = t & 63;
    const int lg = l >> 4, lr = l & 15;
    const int wr = w >> 1, wc = w & 1;

    const unsigned short* gA = Am + (size_t)by*64*D_;
    const unsigned short* gB = Bm + (size_t)bx*128*D_;

    const int srow = l >> 3;
    const int schk = (l & 7) ^ srow;

#define STAGE(buf, k0)                                                         \
    _Pragma("unroll")                                                          \
    for (int i_ = 0; i_ < 2; ++i_) {                                           \
        const int rowA_ = 16*w + 8*i_ + srow;                                  \
        GLOAD16(gA + (size_t)rowA_*D_ + (k0) + 8*schk, &As[buf][(16*w + 8*i_)*64]); \
    }                                                                          \
    _Pragma("unroll")                                                          \
    for (int i_ = 0; i_ < 4; ++i_) {                                           \
        const int rowB_ = 32*w + 8*i_ + srow;                                  \
        GLOAD16(gB + (size_t)rowB_*D_ + (k0) + 8*schk, &Bs[buf][(32*w + 8*i_)*64]); \
    }

    f32x4 acc[2][4] = {};

    STAGE(0, 0);
    #pragma unroll 1
    for (int kt = 0; kt < 16; ++kt) {
        const int cur = kt & 1;
        if (kt < 15) {
            STAGE(cur ^ 1, 64*(kt + 1));
            asm volatile("s_waitcnt vmcnt(6)" ::: "memory");
        } else {
            asm volatile("s_waitcnt vmcnt(0)" ::: "memory");
        }
        __builtin_amdgcn_s_barrier();

        #pragma unroll
        for (int kk = 0; kk < 2; ++kk) {
            s16x8 af[2], bfr[4];
            #pragma unroll
            for (int m = 0; m < 2; ++m) {
                const int row = 32*wr + 16*m + lr;
                af[m] = *(const s16x8*)&As[cur][row*64 + 8*((lg + 4*kk) ^ (row & 7))];
            }
            #pragma unroll
            for (int n = 0; n < 4; ++n) {
                const int col = 64*wc + 16*n + lr;
                bfr[n] = *(const s16x8*)&Bs[cur][col*64 + 8*((lg + 4*kk) ^ (col & 7))];
            }
            #pragma unroll
            for (int m = 0; m < 2; ++m)
                #pragma unroll
                for (int n = 0; n < 4; ++n)
                    acc[m][n] = MFMA16(af[m], bfr[n], acc[m][n]);
        }
        asm volatile("s_waitcnt lgkmcnt(0)" ::: "memory");
        __builtin_amdgcn_s_barrier();
    }
#undef STAGE

    if (MODE == 1) {
        #pragma unroll
        for (int m = 0; m < 2; ++m)
            #pragma unroll
            for (int r = 0; r < 4; ++r) {
                const int row = by*64 + 32*wr + 16*m + 4*lg + r;
                #pragma unroll
                for (int n = 0; n < 4; ++n)
                    outf[(size_t)row*D_ + bx*128 + 64*wc + 16*n + lr] = acc[m][n][r];
            }
        return;
    }

    if (bx < 10) {   // Q (bx<8) or K (bx 8,9): rope; partner dd^32 = acc[m][n^2]
        const float CQ = 0.18033688011112044f;   // (1/8)*log2(e), folded into Q
        #pragma unroll
        for (int m = 0; m < 2; ++m) {
            #pragma unroll
            for (int r = 0; r < 4; ++r) {
                const int row = by*64 + 32*wr + 16*m + 4*lg + r;
                const int b = row >> 11, s = row & (S_ - 1);
                const float c_lo = cost[s*32 + lr],      s_lo = sint[s*32 + lr];
                const float c_hi = cost[s*32 + 16 + lr], s_hi = sint[s*32 + 16 + lr];
                unsigned short vals[4];
                #pragma unroll
                for (int n = 0; n < 4; ++n) {
                    const float cc = (n & 1) ? c_hi : c_lo;
                    const float sn = (n & 1) ? s_hi : s_lo;
                    const float self = acc[m][n][r], part = acc[m][n ^ 2][r];
                    float rv = (n < 2) ? fmaf(self, cc, -part*sn)
                                       : fmaf(self, cc,  part*sn);
                    if (bx < 8) rv *= CQ;
                    vals[n] = f2b(rv);
                }
                size_t base;
                unsigned short* dst;
                if (bx < 8) {
                    const int hh = 2*bx + wc;
                    const int hp = (hh & 3)*4 + (hh >> 2);  // swapaxes(2,3)
                    base = (((size_t)b*H_ + hp)*S_ + s)*HD_;
                    dst = qr;
                } else {
                    const int g = (bx - 8)*2 + wc;
                    base = (((size_t)b*G_ + g)*S_ + s)*HD_;
                    dst = kr;
                }
                #pragma unroll
                for (int n = 0; n < 4; ++n) dst[base + 16*n + lr] = vals[n];
            }
        }
    } else {         // V: store transposed vt[b][g][dd][s]
        const int g = (bx - 10)*2 + wc;
        #pragma unroll
        for (int m = 0; m < 2; ++m) {
            const int row0 = by*64 + 32*wr + 16*m + 4*lg;
            const int b = row0 >> 11, s0 = row0 & (S_ - 1);
            #pragma unroll
            for (int n = 0; n < 4; ++n) {
                const int dd = 16*n + lr;
                u16x4 v;
                #pragma unroll
                for (int r = 0; r < 4; ++r) v[r] = f2b(acc[m][n][r]);
                *(u16x4*)&vt[(((size_t)b*G_ + g)*HD_ + dd)*S_ + s0] = v;
            }
        }
    }
}

// ---------------- MFMA flash attention, IN-BLOCK split-K2 -------------------
// 512 threads = 8 waves: waves 0-3 do keys [0,1024), waves 4-7 do [1024,2048),
// each wave owns 32 q-rows (same rows in both halves). Max-free softmax
// (Q pre-scaled by (1/8)*log2e), l via ones-MFMA. Partials combined through
// LDS at epilogue (overlay on K buffers) -> attnb written directly.
__device__ __forceinline__ void stage64(const unsigned short* Kp, const unsigned short* Vp,
                                        unsigned short* ks, unsigned short* vs,
                                        int key0, int w, int l)
{
    const int srow = l >> 3;            // 0..7
    const int schk = (l & 7) ^ srow;    // pre-swizzled 16B chunk
    #pragma unroll
    for (int i = 0; i < 2; ++i) {
        const int row = 16*w + 8*i + srow;                 // row & 7 == srow
        GLOAD16(Kp + ((size_t)(key0 + row))*HD_ + 8*schk, ks + (16*w + 8*i)*64);
        GLOAD16(Vp + (size_t)row*S_ + key0 + 8*schk,      vs + (16*w + 8*i)*64);
    }
}

__global__ __launch_bounds__(512, 4)
void flash_attn_mfma(const unsigned short* __restrict__ qr,
                     const unsigned short* __restrict__ kr,
                     const unsigned short* __restrict__ vt,
                     unsigned short* __restrict__ attnb)
{
    __shared__ unsigned short Ks[2][2][64*64];   // [half][dbuf] 32 KB
    __shared__ unsigned short Vs[2][2][64*64];   // 32 KB

    const int bid  = blockIdx.x;
    const int cpx  = gridDim.x >> 3;
    const int swz  = (bid & 7)*cpx + (bid >> 3);   // XCD-chunked
    const int qt   = swz & 15;
    const int h    = (swz >> 4) & 15;
    const int b    = swz >> 8;
    const int g    = h >> 2;
    const int t    = threadIdx.x;
    const int w8   = t >> 6;          // 0..7
    const int half = w8 >> 2;
    const int w    = w8 & 3;
    const int l    = t & 63;
    const int hi   = l >> 5;
    const int li   = l & 31;

    const unsigned short* Qp = qr + (((size_t)b*H_ + h)*S_ + (size_t)qt*128 + w*32)*HD_;
    const unsigned short* Kp = kr + ((size_t)b*G_ + g)*(size_t)S_*HD_ + (size_t)half*1024*HD_;
    const unsigned short* Vp = vt + ((size_t)b*G_ + g)*(size_t)HD_*S_ + half*1024;

    s16x8 qf[4];
    #pragma unroll
    for (int kk = 0; kk < 4; ++kk)
        qf[kk] = *(const s16x8*)(Qp + (size_t)li*HD_ + 16*kk + 8*hi);

    s16x8 ones;
    #pragma unroll
    for (int e = 0; e < 8; ++e) ones[e] = (short)0x3F80;   // bf16 1.0

    f32x16 o[2], o_l;
    #pragma unroll
    for (int e = 0; e < 16; ++e) { o[0][e] = 0.f; o[1][e] = 0.f; o_l[e] = 0.f; }

    const int NT = 1024/64;   // 16 phases over this half's key range
    stage64(Kp, Vp, Ks[half][0], Vs[half][0], 0, w, l);

    #pragma unroll 1
    for (int kt = 0; kt < NT; ++kt) {
        const int cur = kt & 1;
        if (kt + 1 < NT) {
            stage64(Kp, Vp, Ks[half][cur^1], Vs[half][cur^1], 64*(kt + 1), w, l);
            asm volatile("s_waitcnt vmcnt(4)" ::: "memory");
        } else {
            asm volatile("s_waitcnt vmcnt(0)" ::: "memory");
        }
        __builtin_amdgcn_s_barrier();

        // ---- QK^T: 64 keys = 2 x 32-key subtiles, independent chains ----
        f32x16 sc[2];
        #pragma unroll
        for (int q4 = 0; q4 < 2; ++q4)
            #pragma unroll
            for (int e = 0; e < 16; ++e) sc[q4][e] = 0.f;

        __builtin_amdgcn_s_setprio(1);
        #pragma unroll
        for (int kk = 0; kk < 4; ++kk) {
            const int chk = 8*((hi + 2*kk) ^ (li & 7));
            #pragma unroll
            for (int q4 = 0; q4 < 2; ++q4) {
                s16x8 kf = *(const s16x8*)&Ks[half][cur][(32*q4 + li)*64 + chk];
                sc[q4] = MFMA32(kf, qf[kk], sc[q4]);
            }
        }
        __builtin_amdgcn_s_setprio(0);

        // ---- P = exp2(sc), 32 batched transcendentals ----
        #pragma unroll
        for (int q4 = 0; q4 < 2; ++q4)
            #pragma unroll
            for (int e = 0; e < 16; ++e)
                sc[q4][e] = __builtin_amdgcn_exp2f(sc[q4][e]);

        // ---- pack (cvt_pk + permlane32_swap) + PV + l-via-MFMA ----
        __builtin_amdgcn_s_setprio(1);
        #pragma unroll
        for (int q4 = 0; q4 < 2; ++q4) {
            #pragma unroll
            for (int s2 = 0; s2 < 2; ++s2) {
                unsigned a0 = cvtpk(sc[q4][8*s2+0], sc[q4][8*s2+1]);
                unsigned a1 = cvtpk(sc[q4][8*s2+2], sc[q4][8*s2+3]);
                unsigned a2 = cvtpk(sc[q4][8*s2+4], sc[q4][8*s2+5]);
                unsigned a3 = cvtpk(sc[q4][8*s2+6], sc[q4][8*s2+7]);
                plswap(a0, a2); plswap(a1, a3);
                u32x4 aw = {a0, a1, a2, a3};
                s16x8 paf = __builtin_bit_cast(s16x8, aw);
                const int ks = 2*q4 + s2;            // 16-key slice in tile
                #pragma unroll
                for (int dt = 0; dt < 2; ++dt) {
                    const int d = li + 32*dt;
                    s16x8 vf = *(const s16x8*)&Vs[half][cur][d*64 + 8*((hi + 2*ks) ^ (li & 7))];
                    o[dt] = MFMA32(paf, vf, o[dt]);
                }
                o_l = MFMA32(paf, ones, o_l);        // row-sum on matrix pipe
            }
        }
        __builtin_amdgcn_s_setprio(0);

        asm volatile("s_waitcnt lgkmcnt(0)" ::: "memory");
        __builtin_amdgcn_s_barrier();
    }

    // ---- epilogue: combine the two halves through LDS ----------------------
    float* ocomb = (float*)&Ks[0][0][0];    // 128 q x 64 d f32 = 32 KB
    float* lcomb = (float*)&Vs[0][0][0];    // 128 f32
    __syncthreads();                        // all compute done before overlay

    if (half == 1) {
        #pragma unroll
        for (int r = 0; r < 16; ++r) {
            const int qq  = (r & 3) + 8*(r >> 2) + 4*hi;
            const int row = w*32 + qq;
            ocomb[row*64 + li]      = o[0][r];
            ocomb[row*64 + li + 32] = o[1][r];
            if (li == 0) lcomb[row] = o_l[r];
        }
    }
    __syncthreads();
    if (half == 0) {
        #pragma unroll
        for (int r = 0; r < 16; ++r) {
            const int qq  = (r & 3) + 8*(r >> 2) + 4*hi;
            const int row = w*32 + qq;
            const int s   = qt*128 + row;
            const float inv = 1.0f / (o_l[r] + lcomb[row]);
            const float v0 = (o[0][r] + ocomb[row*64 + li])      * inv;
            const float v1 = (o[1][r] + ocomb[row*64 + li + 32]) * inv;
            attnb[((size_t)b*S_ + s)*D_ + h*HD_ + li]      = f2b(v0);
            attnb[((size_t)b*S_ + s)*D_ + h*HD_ + li + 32] = f2b(v1);
        }
    }
}

extern "C" void kernel_launch(void* const* d_in, const int* in_sizes, int n_in,
                              void* d_out, int out_size, void* d_ws, size_t ws_size,
                              hipStream_t stream)
{
    const float* x  = (const float*)d_in[0];
    const float* Wq = (const float*)d_in[1];
    const float* Wk = (const float*)d_in[2];
    const float* Wv = (const float*)d_in[3];
    const float* Wo = (const float*)d_in[4];
    float* out = (float*)d_out;

    char* p = (char*)d_ws;
    unsigned short* xb    = (unsigned short*)p; p += (size_t)B_*S_*D_*2;      // 8 MB
    unsigned short* wb    = (unsigned short*)p; p += (size_t)1536*1024*2;     // 3 MB
    unsigned short* wob   = (unsigned short*)p; p += (size_t)1024*1024*2;     // 2 MB
    unsigned short* qr    = (unsigned short*)p; p += (size_t)B_*H_*S_*HD_*2;  // 8 MB
    unsigned short* kr    = (unsigned short*)p; p += (size_t)B_*G_*S_*HD_*2;  // 2 MB
    unsigned short* vt    = (unsigned short*)p; p += (size_t)B_*G_*HD_*S_*2;  // 2 MB
    unsigned short* attnb = (unsigned short*)p; p += (size_t)B_*S_*D_*2;      // 8 MB
    float* cost = (float*)p; p += (size_t)S_*32*4;
    float* sint = (float*)p;

    prep_all<<<6720, 256, 0, stream>>>(x, Wq, Wk, Wv, Wo, xb, wb, wob, cost, sint);
    gemm_mfma<0><<<64*12, 256, 0, stream>>>(xb, wb, qr, kr, vt, nullptr, cost, sint, 12);
    flash_attn_mfma<<<B_*H_*(S_/128), 512, 0, stream>>>(qr, kr, vt, attnb);
    gemm_mfma<1><<<64*8, 256, 0, stream>>>(attnb, wob, nullptr, nullptr, nullptr, out, cost, sint, 8);
}

// Round 13
// 92.560 us; speedup vs baseline: 1.1413x; 1.0709x over previous
//
#include <hip/hip_runtime.h>
#include <hip/hip_bf16.h>
#include <math.h>

#define B_ 2
#define S_ 2048
#define D_ 1024
#define H_ 16
#define G_ 4
#define HD_ 64

typedef float f32x4  __attribute__((ext_vector_type(4)));
typedef float f32x16 __attribute__((ext_vector_type(16)));
typedef short s16x8  __attribute__((ext_vector_type(8)));
typedef unsigned short u16x4 __attribute__((ext_vector_type(4)));
typedef unsigned int   u32x4 __attribute__((ext_vector_type(4)));

__device__ __forceinline__ unsigned short f2b(float f) {
    __hip_bfloat16 h = __float2bfloat16(f);
    return __builtin_bit_cast(unsigned short, h);
}
__device__ __forceinline__ unsigned cvtpk(float lo, float hi) {
    unsigned r;
    asm("v_cvt_pk_bf16_f32 %0, %1, %2" : "=v"(r) : "v"(lo), "v"(hi));
    return r;
}
__device__ __forceinline__ void plswap(unsigned &a, unsigned &b) {
    asm("v_permlane32_swap_b32 %0, %1" : "+v"(a), "+v"(b));
}

#define MFMA16(a, b, c) __builtin_amdgcn_mfma_f32_16x16x32_bf16(a, b, c, 0, 0, 0)
#define MFMA32(a, b, c) __builtin_amdgcn_mfma_f32_32x32x16_bf16(a, b, c, 0, 0, 0)

#define GLOAD16(gp, lp) __builtin_amdgcn_global_load_lds(                      \
    (const __attribute__((address_space(1))) void*)(gp),                      \
    (__attribute__((address_space(3))) void*)(lp), 16, 0, 0)

// ---------------- prep: bf16 casts + pooled K/V weights + rope tables -------
__global__ __launch_bounds__(256)
void prep_all(const float* __restrict__ x,  const float* __restrict__ Wq,
              const float* __restrict__ Wk, const float* __restrict__ Wv,
              const float* __restrict__ Wo,
              unsigned short* __restrict__ xb, unsigned short* __restrict__ wb,
              unsigned short* __restrict__ wob,
              float* __restrict__ cost, float* __restrict__ sint)
{
    const int NQ_WB = (1536*1024)/4;
    const int NQ_WO = (1024*1024)/4;
    const int NQ_X  = (B_*S_*D_)/4;
    int q = blockIdx.x*256 + threadIdx.x;
    if (q < NQ_WB) {
        const int idx = q*4, row = idx >> 10, c = idx & 1023;
        u16x4 o;
        if (row < 1024) {
            f32x4 v = *(const f32x4*)&Wq[(size_t)row*1024 + c];
            #pragma unroll
            for (int j = 0; j < 4; ++j) o[j] = f2b(v[j]);
        } else {
            const int rd = row - 1024, kv = rd >> 8, gd = rd & 255;
            const int g = gd >> 6, d = gd & 63;
            const float* W = kv ? Wv : Wk;
            f32x4 sum = {0.f, 0.f, 0.f, 0.f};
            #pragma unroll
            for (int p = 0; p < 4; ++p)
                sum += *(const f32x4*)&W[(size_t)((g*4 + p)*64 + d)*1024 + c];
            #pragma unroll
            for (int j = 0; j < 4; ++j) o[j] = f2b(sum[j]*0.25f);
        }
        *(u16x4*)&wb[idx] = o;
        return;
    }
    q -= NQ_WB;
    if (q < NQ_WO) {
        const int idx = q*4;
        f32x4 v = *(const f32x4*)&Wo[idx];
        u16x4 o;
        #pragma unroll
        for (int j = 0; j < 4; ++j) o[j] = f2b(v[j]);
        *(u16x4*)&wob[idx] = o;
        return;
    }
    q -= NQ_WO;
    if (q < NQ_X) {
        const int idx = q*4;
        f32x4 v = *(const f32x4*)&x[idx];
        u16x4 o;
        #pragma unroll
        for (int j = 0; j < 4; ++j) o[j] = f2b(v[j]);
        *(u16x4*)&xb[idx] = o;
        return;
    }
    q -= NQ_X;
    if (q < (S_*32)/4) {
        const int idx = q*4, s = idx >> 5, f0 = idx & 31;
        #pragma unroll
        for (int j = 0; j < 4; ++j) {
            const float f = (float)(f0 + j);
            const float fr = (float)s * powf(10000.0f, -f*(1.0f/32.0f));
            cost[idx + j] = cosf(fr);
            sint[idx + j] = sinf(fr);
        }
    }
}

// ---------------- MFMA GEMM: C = A(Mx1024) * B(Nx1024)^T, 64x128 tile -------
// MODE 0: fused QKV epilogue (bx<8: Q rope+permute+*C; bx<10: K rope; else V^T)
// MODE 1: fp32 store (O-projection)
template<int MODE>
__global__ __launch_bounds__(256)
void gemm_mfma(const unsigned short* __restrict__ Am,
               const unsigned short* __restrict__ Bm,
               unsigned short* __restrict__ qr,
               unsigned short* __restrict__ kr,
               unsigned short* __restrict__ vt,
               float* __restrict__ outf,
               const float* __restrict__ cost,
               const float* __restrict__ sint,
               int nbx)
{
    __shared__ unsigned short As[2][64*64];    // 16 KB
    __shared__ unsigned short Bs[2][128*64];   // 32 KB

    const int nwg = gridDim.x;
    const int cpx = nwg >> 3;
    const int bid = blockIdx.x;
    const int swz = (bid & 7)*cpx + (bid >> 3);     // XCD-chunked (bijective)
    const int bx = swz % nbx, by = swz / nbx;

    const int t  = threadIdx.x;
    const int w  = t >> 6, l = t & 63;
    const int lg = l >> 4, lr = l & 15;
    const int wr = w >> 1, wc = w & 1;

    const unsigned short* gA = Am + (size_t)by*64*D_;
    const unsigned short* gB = Bm + (size_t)bx*128*D_;

    const int srow = l >> 3;
    const int schk = (l & 7) ^ srow;

#define STAGE(buf, k0)                                                         \
    _Pragma("unroll")                                                          \
    for (int i_ = 0; i_ < 2; ++i_) {                                           \
        const int rowA_ = 16*w + 8*i_ + srow;                                  \
        GLOAD16(gA + (size_t)rowA_*D_ + (k0) + 8*schk, &As[buf][(16*w + 8*i_)*64]); \
    }                                                                          \
    _Pragma("unroll")                                                          \
    for (int i_ = 0; i_ < 4; ++i_) {                                           \
        const int rowB_ = 32*w + 8*i_ + srow;                                  \
        GLOAD16(gB + (size_t)rowB_*D_ + (k0) + 8*schk, &Bs[buf][(32*w + 8*i_)*64]); \
    }

    f32x4 acc[2][4] = {};

    STAGE(0, 0);
    #pragma unroll 1
    for (int kt = 0; kt < 16; ++kt) {
        const int cur = kt & 1;
        if (kt < 15) {
            STAGE(cur ^ 1, 64*(kt + 1));
            asm volatile("s_waitcnt vmcnt(6)" ::: "memory");
        } else {
            asm volatile("s_waitcnt vmcnt(0)" ::: "memory");
        }
        __builtin_amdgcn_s_barrier();

        #pragma unroll
        for (int kk = 0; kk < 2; ++kk) {
            s16x8 af[2], bfr[4];
            #pragma unroll
            for (int m = 0; m < 2; ++m) {
                const int row = 32*wr + 16*m + lr;
                af[m] = *(const s16x8*)&As[cur][row*64 + 8*((lg + 4*kk) ^ (row & 7))];
            }
            #pragma unroll
            for (int n = 0; n < 4; ++n) {
                const int col = 64*wc + 16*n + lr;
                bfr[n] = *(const s16x8*)&Bs[cur][col*64 + 8*((lg + 4*kk) ^ (col & 7))];
            }
            #pragma unroll
            for (int m = 0; m < 2; ++m)
                #pragma unroll
                for (int n = 0; n < 4; ++n)
                    acc[m][n] = MFMA16(af[m], bfr[n], acc[m][n]);
        }
        asm volatile("s_waitcnt lgkmcnt(0)" ::: "memory");
        __builtin_amdgcn_s_barrier();
    }
#undef STAGE

    if (MODE == 1) {
        #pragma unroll
        for (int m = 0; m < 2; ++m)
            #pragma unroll
            for (int r = 0; r < 4; ++r) {
                const int row = by*64 + 32*wr + 16*m + 4*lg + r;
                #pragma unroll
                for (int n = 0; n < 4; ++n)
                    outf[(size_t)row*D_ + bx*128 + 64*wc + 16*n + lr] = acc[m][n][r];
            }
        return;
    }

    if (bx < 10) {   // Q (bx<8) or K (bx 8,9): rope; partner dd^32 = acc[m][n^2]
        const float CQ = 0.18033688011112044f;   // (1/8)*log2(e), folded into Q
        #pragma unroll
        for (int m = 0; m < 2; ++m) {
            #pragma unroll
            for (int r = 0; r < 4; ++r) {
                const int row = by*64 + 32*wr + 16*m + 4*lg + r;
                const int b = row >> 11, s = row & (S_ - 1);
                const float c_lo = cost[s*32 + lr],      s_lo = sint[s*32 + lr];
                const float c_hi = cost[s*32 + 16 + lr], s_hi = sint[s*32 + 16 + lr];
                unsigned short vals[4];
                #pragma unroll
                for (int n = 0; n < 4; ++n) {
                    const float cc = (n & 1) ? c_hi : c_lo;
                    const float sn = (n & 1) ? s_hi : s_lo;
                    const float self = acc[m][n][r], part = acc[m][n ^ 2][r];
                    float rv = (n < 2) ? fmaf(self, cc, -part*sn)
                                       : fmaf(self, cc,  part*sn);
                    if (bx < 8) rv *= CQ;
                    vals[n] = f2b(rv);
                }
                size_t base;
                unsigned short* dst;
                if (bx < 8) {
                    const int hh = 2*bx + wc;
                    const int hp = (hh & 3)*4 + (hh >> 2);  // swapaxes(2,3)
                    base = (((size_t)b*H_ + hp)*S_ + s)*HD_;
                    dst = qr;
                } else {
                    const int g = (bx - 8)*2 + wc;
                    base = (((size_t)b*G_ + g)*S_ + s)*HD_;
                    dst = kr;
                }
                #pragma unroll
                for (int n = 0; n < 4; ++n) dst[base + 16*n + lr] = vals[n];
            }
        }
    } else {         // V: store transposed vt[b][g][dd][s]
        const int g = (bx - 10)*2 + wc;
        #pragma unroll
        for (int m = 0; m < 2; ++m) {
            const int row0 = by*64 + 32*wr + 16*m + 4*lg;
            const int b = row0 >> 11, s0 = row0 & (S_ - 1);
            #pragma unroll
            for (int n = 0; n < 4; ++n) {
                const int dd = 16*n + lr;
                u16x4 v;
                #pragma unroll
                for (int r = 0; r < 4; ++r) v[r] = f2b(acc[m][n][r]);
                *(u16x4*)&vt[(((size_t)b*G_ + g)*HD_ + dd)*S_ + s0] = v;
            }
        }
    }
}

// ---------------- MFMA flash attention, intra-wave dual-stream split-K2 -----
// 4 waves x 32 q-rows. Each WAVE runs two independent pipelines: stream A =
// keys [0,1024), stream B = [1024,2048). Program order QK_A,QK_B,exp_A,
// PV_A,exp_B,PV_B lets one stream's VALU overlap the other's MFMA drain
// (single-wave dual-pipe ILP). Split-K combine is IN-REGISTER at epilogue
// (o=oA+oB, l=lA+lB) -> attnb direct, no combine pass. Max-free softmax,
// l via ones-MFMA. One barrier pair per 128 keys.
__device__ __forceinline__ void stage64(const unsigned short* Kp, const unsigned short* Vp,
                                        unsigned short* ks, unsigned short* vs,
                                        int key0, int w, int l)
{
    const int srow = l >> 3;            // 0..7
    const int schk = (l & 7) ^ srow;    // pre-swizzled 16B chunk
    #pragma unroll
    for (int i = 0; i < 2; ++i) {
        const int row = 16*w + 8*i + srow;                 // row & 7 == srow
        GLOAD16(Kp + ((size_t)(key0 + row))*HD_ + 8*schk, ks + (16*w + 8*i)*64);
        GLOAD16(Vp + (size_t)row*S_ + key0 + 8*schk,      vs + (16*w + 8*i)*64);
    }
}

__global__ __launch_bounds__(256, 2)
void flash_attn_mfma(const unsigned short* __restrict__ qr,
                     const unsigned short* __restrict__ kr,
                     const unsigned short* __restrict__ vt,
                     unsigned short* __restrict__ attnb)
{
    __shared__ unsigned short KsA[2][64*64];   // 16 KB
    __shared__ unsigned short VsA[2][64*64];   // 16 KB
    __shared__ unsigned short KsB[2][64*64];   // 16 KB
    __shared__ unsigned short VsB[2][64*64];   // 16 KB

    const int bid = blockIdx.x;
    const int cpx = gridDim.x >> 3;
    const int swz = (bid & 7)*cpx + (bid >> 3);   // XCD-chunked
    const int qt  = swz & 15;
    const int h   = (swz >> 4) & 15;
    const int b   = swz >> 8;
    const int g   = h >> 2;
    const int t   = threadIdx.x;
    const int w   = t >> 6;
    const int l   = t & 63;
    const int hi  = l >> 5;
    const int li  = l & 31;

    const unsigned short* Qp  = qr + (((size_t)b*H_ + h)*S_ + (size_t)qt*128 + w*32)*HD_;
    const unsigned short* KpA = kr + ((size_t)b*G_ + g)*(size_t)S_*HD_;
    const unsigned short* VpA = vt + ((size_t)b*G_ + g)*(size_t)HD_*S_;
    const unsigned short* KpB = KpA + (size_t)1024*HD_;
    const unsigned short* VpB = VpA + 1024;

    s16x8 qf[4];
    #pragma unroll
    for (int kk = 0; kk < 4; ++kk)
        qf[kk] = *(const s16x8*)(Qp + (size_t)li*HD_ + 16*kk + 8*hi);

    s16x8 ones;
    #pragma unroll
    for (int e = 0; e < 8; ++e) ones[e] = (short)0x3F80;   // bf16 1.0

    f32x16 oA[2], oB[2], olA, olB;
    #pragma unroll
    for (int e = 0; e < 16; ++e) {
        oA[0][e] = 0.f; oA[1][e] = 0.f; olA[e] = 0.f;
        oB[0][e] = 0.f; oB[1][e] = 0.f; olB[e] = 0.f;
    }

    const int NT = 1024/64;   // 16 iterations; each covers 64 keys PER stream
    stage64(KpA, VpA, KsA[0], VsA[0], 0, w, l);
    stage64(KpB, VpB, KsB[0], VsB[0], 0, w, l);

    #pragma unroll 1
    for (int kt = 0; kt < NT; ++kt) {
        const int cur = kt & 1;
        if (kt + 1 < NT) {
            stage64(KpA, VpA, KsA[cur^1], VsA[cur^1], 64*(kt + 1), w, l);
            stage64(KpB, VpB, KsB[cur^1], VsB[cur^1], 64*(kt + 1), w, l);
            asm volatile("s_waitcnt vmcnt(8)" ::: "memory");
        } else {
            asm volatile("s_waitcnt vmcnt(0)" ::: "memory");
        }
        __builtin_amdgcn_s_barrier();

        // ---- QK^T both streams (16 independent MFMAs fill the pipe) ----
        f32x16 scA[2], scB[2];
        #pragma unroll
        for (int q4 = 0; q4 < 2; ++q4)
            #pragma unroll
            for (int e = 0; e < 16; ++e) { scA[q4][e] = 0.f; scB[q4][e] = 0.f; }

        __builtin_amdgcn_s_setprio(1);
        #pragma unroll
        for (int kk = 0; kk < 4; ++kk) {
            const int chk = 8*((hi + 2*kk) ^ (li & 7));
            #pragma unroll
            for (int q4 = 0; q4 < 2; ++q4) {
                s16x8 kfA = *(const s16x8*)&KsA[cur][(32*q4 + li)*64 + chk];
                scA[q4] = MFMA32(kfA, qf[kk], scA[q4]);
            }
        }
        #pragma unroll
        for (int kk = 0; kk < 4; ++kk) {
            const int chk = 8*((hi + 2*kk) ^ (li & 7));
            #pragma unroll
            for (int q4 = 0; q4 < 2; ++q4) {
                s16x8 kfB = *(const s16x8*)&KsB[cur][(32*q4 + li)*64 + chk];
                scB[q4] = MFMA32(kfB, qf[kk], scB[q4]);
            }
        }
        __builtin_amdgcn_s_setprio(0);

        // ---- stream A: exp (overlaps QK_B's MFMA drain) ----
        #pragma unroll
        for (int q4 = 0; q4 < 2; ++q4)
            #pragma unroll
            for (int e = 0; e < 16; ++e)
                scA[q4][e] = __builtin_amdgcn_exp2f(scA[q4][e]);

        // ---- stream A: pack + PV + l ----
        __builtin_amdgcn_s_setprio(1);
        #pragma unroll
        for (int q4 = 0; q4 < 2; ++q4) {
            #pragma unroll
            for (int s2 = 0; s2 < 2; ++s2) {
                unsigned a0 = cvtpk(scA[q4][8*s2+0], scA[q4][8*s2+1]);
                unsigned a1 = cvtpk(scA[q4][8*s2+2], scA[q4][8*s2+3]);
                unsigned a2 = cvtpk(scA[q4][8*s2+4], scA[q4][8*s2+5]);
                unsigned a3 = cvtpk(scA[q4][8*s2+6], scA[q4][8*s2+7]);
                plswap(a0, a2); plswap(a1, a3);
                u32x4 aw = {a0, a1, a2, a3};
                s16x8 paf = __builtin_bit_cast(s16x8, aw);
                const int ks = 2*q4 + s2;
                #pragma unroll
                for (int dt = 0; dt < 2; ++dt) {
                    const int d = li + 32*dt;
                    s16x8 vf = *(const s16x8*)&VsA[cur][d*64 + 8*((hi + 2*ks) ^ (li & 7))];
                    oA[dt] = MFMA32(paf, vf, oA[dt]);
                }
                olA = MFMA32(paf, ones, olA);
            }
        }
        __builtin_amdgcn_s_setprio(0);

        // ---- stream B: exp (overlaps PV_A's MFMA drain) ----
        #pragma unroll
        for (int q4 = 0; q4 < 2; ++q4)
            #pragma unroll
            for (int e = 0; e < 16; ++e)
                scB[q4][e] = __builtin_amdgcn_exp2f(scB[q4][e]);

        // ---- stream B: pack + PV + l ----
        __builtin_amdgcn_s_setprio(1);
        #pragma unroll
        for (int q4 = 0; q4 < 2; ++q4) {
            #pragma unroll
            for (int s2 = 0; s2 < 2; ++s2) {
                unsigned b0 = cvtpk(scB[q4][8*s2+0], scB[q4][8*s2+1]);
                unsigned b1 = cvtpk(scB[q4][8*s2+2], scB[q4][8*s2+3]);
                unsigned b2 = cvtpk(scB[q4][8*s2+4], scB[q4][8*s2+5]);
                unsigned b3 = cvtpk(scB[q4][8*s2+6], scB[q4][8*s2+7]);
                plswap(b0, b2); plswap(b1, b3);
                u32x4 bw = {b0, b1, b2, b3};
                s16x8 pbf = __builtin_bit_cast(s16x8, bw);
                const int ks = 2*q4 + s2;
                #pragma unroll
                for (int dt = 0; dt < 2; ++dt) {
                    const int d = li + 32*dt;
                    s16x8 vf = *(const s16x8*)&VsB[cur][d*64 + 8*((hi + 2*ks) ^ (li & 7))];
                    oB[dt] = MFMA32(pbf, vf, oB[dt]);
                }
                olB = MFMA32(pbf, ones, olB);
            }
        }
        __builtin_amdgcn_s_setprio(0);

        asm volatile("s_waitcnt lgkmcnt(0)" ::: "memory");
        __builtin_amdgcn_s_barrier();
    }

    // ---- epilogue: in-register combine of the two streams ------------------
    #pragma unroll
    for (int r = 0; r < 16; ++r) {
        const int qq = (r & 3) + 8*(r >> 2) + 4*hi;
        const int s  = qt*128 + w*32 + qq;
        const float inv = 1.0f / (olA[r] + olB[r]);
        #pragma unroll
        for (int dt = 0; dt < 2; ++dt)
            attnb[((size_t)b*S_ + s)*D_ + h*HD_ + li + 32*dt] =
                f2b((oA[dt][r] + oB[dt][r]) * inv);
    }
}

extern "C" void kernel_launch(void* const* d_in, const int* in_sizes, int n_in,
                              void* d_out, int out_size, void* d_ws, size_t ws_size,
                              hipStream_t stream)
{
    const float* x  = (const float*)d_in[0];
    const float* Wq = (const float*)d_in[1];
    const float* Wk = (const float*)d_in[2];
    const float* Wv = (const float*)d_in[3];
    const float* Wo = (const float*)d_in[4];
    float* out = (float*)d_out;

    char* p = (char*)d_ws;
    unsigned short* xb    = (unsigned short*)p; p += (size_t)B_*S_*D_*2;      // 8 MB
    unsigned short* wb    = (unsigned short*)p; p += (size_t)1536*1024*2;     // 3 MB
    unsigned short* wob   = (unsigned short*)p; p += (size_t)1024*1024*2;     // 2 MB
    unsigned short* qr    = (unsigned short*)p; p += (size_t)B_*H_*S_*HD_*2;  // 8 MB
    unsigned short* kr    = (unsigned short*)p; p += (size_t)B_*G_*S_*HD_*2;  // 2 MB
    unsigned short* vt    = (unsigned short*)p; p += (size_t)B_*G_*HD_*S_*2;  // 2 MB
    unsigned short* attnb = (unsigned short*)p; p += (size_t)B_*S_*D_*2;      // 8 MB
    float* cost = (float*)p; p += (size_t)S_*32*4;
    float* sint = (float*)p;

    prep_all<<<6720, 256, 0, stream>>>(x, Wq, Wk, Wv, Wo, xb, wb, wob, cost, sint);
    gemm_mfma<0><<<64*12, 256, 0, stream>>>(xb, wb, qr, kr, vt, nullptr, cost, sint, 12);
    flash_attn_mfma<<<B_*H_*(S_/128), 256, 0, stream>>>(qr, kr, vt, attnb);
    gemm_mfma<1><<<64*8, 256, 0, stream>>>(attnb, wob, nullptr, nullptr, nullptr, out, cost, sint, 8);
}

// Round 14
// 91.759 us; speedup vs baseline: 1.1513x; 1.0087x over previous
//
#include <hip/hip_runtime.h>
#include <hip/hip_bf16.h>
#include <math.h>

#define B_ 2
#define S_ 2048
#define D_ 1024
#define H_ 16
#define G_ 4
#define HD_ 64

typedef float f32x4  __attribute__((ext_vector_type(4)));
typedef float f32x16 __attribute__((ext_vector_type(16)));
typedef short s16x8  __attribute__((ext_vector_type(8)));
typedef unsigned short u16x4 __attribute__((ext_vector_type(4)));
typedef unsigned int   u32x4 __attribute__((ext_vector_type(4)));

__device__ __forceinline__ unsigned short f2b(float f) {
    __hip_bfloat16 h = __float2bfloat16(f);
    return __builtin_bit_cast(unsigned short, h);
}
__device__ __forceinline__ unsigned cvtpk(float lo, float hi) {
    unsigned r;
    asm("v_cvt_pk_bf16_f32 %0, %1, %2" : "=v"(r) : "v"(lo), "v"(hi));
    return r;
}
__device__ __forceinline__ void plswap(unsigned &a, unsigned &b) {
    asm("v_permlane32_swap_b32 %0, %1" : "+v"(a), "+v"(b));
}

#define MFMA16(a, b, c) __builtin_amdgcn_mfma_f32_16x16x32_bf16(a, b, c, 0, 0, 0)
#define MFMA32(a, b, c) __builtin_amdgcn_mfma_f32_32x32x16_bf16(a, b, c, 0, 0, 0)

#define GLOAD16(gp, lp) __builtin_amdgcn_global_load_lds(                      \
    (const __attribute__((address_space(1))) void*)(gp),                      \
    (__attribute__((address_space(3))) void*)(lp), 16, 0, 0)

// ---------------- prep: bf16 casts + pooled K/V weights + rope tables -------
__global__ __launch_bounds__(256)
void prep_all(const float* __restrict__ x,  const float* __restrict__ Wq,
              const float* __restrict__ Wk, const float* __restrict__ Wv,
              const float* __restrict__ Wo,
              unsigned short* __restrict__ xb, unsigned short* __restrict__ wb,
              unsigned short* __restrict__ wob,
              float* __restrict__ cost, float* __restrict__ sint)
{
    const int NQ_WB = (1536*1024)/4;
    const int NQ_WO = (1024*1024)/4;
    const int NQ_X  = (B_*S_*D_)/4;
    int q = blockIdx.x*256 + threadIdx.x;
    if (q < NQ_WB) {
        const int idx = q*4, row = idx >> 10, c = idx & 1023;
        u16x4 o;
        if (row < 1024) {
            f32x4 v = *(const f32x4*)&Wq[(size_t)row*1024 + c];
            #pragma unroll
            for (int j = 0; j < 4; ++j) o[j] = f2b(v[j]);
        } else {
            const int rd = row - 1024, kv = rd >> 8, gd = rd & 255;
            const int g = gd >> 6, d = gd & 63;
            const float* W = kv ? Wv : Wk;
            f32x4 sum = {0.f, 0.f, 0.f, 0.f};
            #pragma unroll
            for (int p = 0; p < 4; ++p)
                sum += *(const f32x4*)&W[(size_t)((g*4 + p)*64 + d)*1024 + c];
            #pragma unroll
            for (int j = 0; j < 4; ++j) o[j] = f2b(sum[j]*0.25f);
        }
        *(u16x4*)&wb[idx] = o;
        return;
    }
    q -= NQ_WB;
    if (q < NQ_WO) {
        const int idx = q*4;
        f32x4 v = *(const f32x4*)&Wo[idx];
        u16x4 o;
        #pragma unroll
        for (int j = 0; j < 4; ++j) o[j] = f2b(v[j]);
        *(u16x4*)&wob[idx] = o;
        return;
    }
    q -= NQ_WO;
    if (q < NQ_X) {
        const int idx = q*4;
        f32x4 v = *(const f32x4*)&x[idx];
        u16x4 o;
        #pragma unroll
        for (int j = 0; j < 4; ++j) o[j] = f2b(v[j]);
        *(u16x4*)&xb[idx] = o;
        return;
    }
    q -= NQ_X;
    if (q < (S_*32)/4) {
        const int idx = q*4, s = idx >> 5, f0 = idx & 31;
        #pragma unroll
        for (int j = 0; j < 4; ++j) {
            const float f = (float)(f0 + j);
            const float fr = (float)s * powf(10000.0f, -f*(1.0f/32.0f));
            cost[idx + j] = cosf(fr);
            sint[idx + j] = sinf(fr);
        }
    }
}

// ---------------- MFMA GEMM: C = A(Mx1024) * B(Nx1024)^T, 64x128 tile -------
// MODE 0: fused QKV epilogue (bx<8: Q rope+permute+*C; bx<10: K rope; else V^T)
// MODE 1: fp32 store (O-projection)
template<int MODE>
__global__ __launch_bounds__(256)
void gemm_mfma(const unsigned short* __restrict__ Am,
               const unsigned short* __restrict__ Bm,
               unsigned short* __restrict__ qr,
               unsigned short* __restrict__ kr,
               unsigned short* __restrict__ vt,
               float* __restrict__ outf,
               const float* __restrict__ cost,
               const float* __restrict__ sint,
               int nbx)
{
    __shared__ unsigned short As[2][64*64];    // 16 KB
    __shared__ unsigned short Bs[2][128*64];   // 32 KB

    const int nwg = gridDim.x;
    const int cpx = nwg >> 3;
    const int bid = blockIdx.x;
    const int swz = (bid & 7)*cpx + (bid >> 3);     // XCD-chunked (bijective)
    const int bx = swz % nbx, by = swz / nbx;

    const int t  = threadIdx.x;
    const int w  = t >> 6, l = t & 63;
    const int lg = l >> 4, lr = l & 15;
    const int wr = w >> 1, wc = w & 1;

    const unsigned short* gA = Am + (size_t)by*64*D_;
    const unsigned short* gB = Bm + (size_t)bx*128*D_;

    const int srow = l >> 3;
    const int schk = (l & 7) ^ srow;

#define STAGE(buf, k0)                                                         \
    _Pragma("unroll")                                                          \
    for (int i_ = 0; i_ < 2; ++i_) {                                           \
        const int rowA_ = 16*w + 8*i_ + srow;                                  \
        GLOAD16(gA + (size_t)rowA_*D_ + (k0) + 8*schk, &As[buf][(16*w + 8*i_)*64]); \
    }                                                                          \
    _Pragma("unroll")                                                          \
    for (int i_ = 0; i_ < 4; ++i_) {                                           \
        const int rowB_ = 32*w + 8*i_ + srow;                                  \
        GLOAD16(gB + (size_t)rowB_*D_ + (k0) + 8*schk, &Bs[buf][(32*w + 8*i_)*64]); \
    }

    f32x4 acc[2][4] = {};

    STAGE(0, 0);
    #pragma unroll 1
    for (int kt = 0; kt < 16; ++kt) {
        const int cur = kt & 1;
        if (kt < 15) {
            STAGE(cur ^ 1, 64*(kt + 1));
            asm volatile("s_waitcnt vmcnt(6)" ::: "memory");
        } else {
            asm volatile("s_waitcnt vmcnt(0)" ::: "memory");
        }
        __builtin_amdgcn_s_barrier();

        #pragma unroll
        for (int kk = 0; kk < 2; ++kk) {
            s16x8 af[2], bfr[4];
            #pragma unroll
            for (int m = 0; m < 2; ++m) {
                const int row = 32*wr + 16*m + lr;
                af[m] = *(const s16x8*)&As[cur][row*64 + 8*((lg + 4*kk) ^ (row & 7))];
            }
            #pragma unroll
            for (int n = 0; n < 4; ++n) {
                const int col = 64*wc + 16*n + lr;
                bfr[n] = *(const s16x8*)&Bs[cur][col*64 + 8*((lg + 4*kk) ^ (col & 7))];
            }
            #pragma unroll
            for (int m = 0; m < 2; ++m)
                #pragma unroll
                for (int n = 0; n < 4; ++n)
                    acc[m][n] = MFMA16(af[m], bfr[n], acc[m][n]);
        }
        asm volatile("s_waitcnt lgkmcnt(0)" ::: "memory");
        __builtin_amdgcn_s_barrier();
    }
#undef STAGE

    if (MODE == 1) {
        #pragma unroll
        for (int m = 0; m < 2; ++m)
            #pragma unroll
            for (int r = 0; r < 4; ++r) {
                const int row = by*64 + 32*wr + 16*m + 4*lg + r;
                #pragma unroll
                for (int n = 0; n < 4; ++n)
                    outf[(size_t)row*D_ + bx*128 + 64*wc + 16*n + lr] = acc[m][n][r];
            }
        return;
    }

    if (bx < 10) {   // Q (bx<8) or K (bx 8,9): rope; partner dd^32 = acc[m][n^2]
        const float CQ = 0.18033688011112044f;   // (1/8)*log2(e), folded into Q
        #pragma unroll
        for (int m = 0; m < 2; ++m) {
            #pragma unroll
            for (int r = 0; r < 4; ++r) {
                const int row = by*64 + 32*wr + 16*m + 4*lg + r;
                const int b = row >> 11, s = row & (S_ - 1);
                const float c_lo = cost[s*32 + lr],      s_lo = sint[s*32 + lr];
                const float c_hi = cost[s*32 + 16 + lr], s_hi = sint[s*32 + 16 + lr];
                unsigned short vals[4];
                #pragma unroll
                for (int n = 0; n < 4; ++n) {
                    const float cc = (n & 1) ? c_hi : c_lo;
                    const float sn = (n & 1) ? s_hi : s_lo;
                    const float self = acc[m][n][r], part = acc[m][n ^ 2][r];
                    float rv = (n < 2) ? fmaf(self, cc, -part*sn)
                                       : fmaf(self, cc,  part*sn);
                    if (bx < 8) rv *= CQ;
                    vals[n] = f2b(rv);
                }
                size_t base;
                unsigned short* dst;
                if (bx < 8) {
                    const int hh = 2*bx + wc;
                    const int hp = (hh & 3)*4 + (hh >> 2);  // swapaxes(2,3)
                    base = (((size_t)b*H_ + hp)*S_ + s)*HD_;
                    dst = qr;
                } else {
                    const int g = (bx - 8)*2 + wc;
                    base = (((size_t)b*G_ + g)*S_ + s)*HD_;
                    dst = kr;
                }
                #pragma unroll
                for (int n = 0; n < 4; ++n) dst[base + 16*n + lr] = vals[n];
            }
        }
    } else {         // V: store transposed vt[b][g][dd][s]
        const int g = (bx - 10)*2 + wc;
        #pragma unroll
        for (int m = 0; m < 2; ++m) {
            const int row0 = by*64 + 32*wr + 16*m + 4*lg;
            const int b = row0 >> 11, s0 = row0 & (S_ - 1);
            #pragma unroll
            for (int n = 0; n < 4; ++n) {
                const int dd = 16*n + lr;
                u16x4 v;
                #pragma unroll
                for (int r = 0; r < 4; ++r) v[r] = f2b(acc[m][n][r]);
                *(u16x4*)&vt[(((size_t)b*G_ + g)*HD_ + dd)*S_ + s0] = v;
            }
        }
    }
}

// ---------------- MFMA flash attention, dual-stream, lean-sync --------------
// 4 waves x 32 q-rows, dual-stream split-K2 in-wave (A=[0,1024), B=[1024,2048)).
// Per iter: ONE barrier (vmcnt(0) -> barrier -> stage(next) -> compute): own
// vmcnt + barrier proves all waves' gloads landed; barrier also proves all
// reads of the buffer about to be overwritten are done. ones-MFMA reduced to
// 1/stream/iter via pa_sum (linearity of MFMA in A). sc chains seeded from a
// live zero vector (no per-iter v_mov zero-init).
__device__ __forceinline__ void stage64(const unsigned short* Kp, const unsigned short* Vp,
                                        unsigned short* ks, unsigned short* vs,
                                        int key0, int w, int l)
{
    const int srow = l >> 3;            // 0..7
    const int schk = (l & 7) ^ srow;    // pre-swizzled 16B chunk
    #pragma unroll
    for (int i = 0; i < 2; ++i) {
        const int row = 16*w + 8*i + srow;                 // row & 7 == srow
        GLOAD16(Kp + ((size_t)(key0 + row))*HD_ + 8*schk, ks + (16*w + 8*i)*64);
        GLOAD16(Vp + (size_t)row*S_ + key0 + 8*schk,      vs + (16*w + 8*i)*64);
    }
}

__global__ __launch_bounds__(256, 2)
void flash_attn_mfma(const unsigned short* __restrict__ qr,
                     const unsigned short* __restrict__ kr,
                     const unsigned short* __restrict__ vt,
                     unsigned short* __restrict__ attnb)
{
    __shared__ unsigned short KsA[2][64*64];   // 16 KB
    __shared__ unsigned short VsA[2][64*64];   // 16 KB
    __shared__ unsigned short KsB[2][64*64];   // 16 KB
    __shared__ unsigned short VsB[2][64*64];   // 16 KB

    const int bid = blockIdx.x;
    const int cpx = gridDim.x >> 3;
    const int swz = (bid & 7)*cpx + (bid >> 3);   // XCD-chunked
    const int qt  = swz & 15;
    const int h   = (swz >> 4) & 15;
    const int b   = swz >> 8;
    const int g   = h >> 2;
    const int t   = threadIdx.x;
    const int w   = t >> 6;
    const int l   = t & 63;
    const int hi  = l >> 5;
    const int li  = l & 31;

    const unsigned short* Qp  = qr + (((size_t)b*H_ + h)*S_ + (size_t)qt*128 + w*32)*HD_;
    const unsigned short* KpA = kr + ((size_t)b*G_ + g)*(size_t)S_*HD_;
    const unsigned short* VpA = vt + ((size_t)b*G_ + g)*(size_t)HD_*S_;
    const unsigned short* KpB = KpA + (size_t)1024*HD_;
    const unsigned short* VpB = VpA + 1024;

    s16x8 qf[4];
    #pragma unroll
    for (int kk = 0; kk < 4; ++kk)
        qf[kk] = *(const s16x8*)(Qp + (size_t)li*HD_ + 16*kk + 8*hi);

    s16x8 ones;
    #pragma unroll
    for (int e = 0; e < 8; ++e) ones[e] = (short)0x3F80;   // bf16 1.0

    f32x16 zf;                                  // live zero C-in for QK chains
    #pragma unroll
    for (int e = 0; e < 16; ++e) zf[e] = 0.f;

    f32x16 oA[2], oB[2], olA, olB;
    #pragma unroll
    for (int e = 0; e < 16; ++e) {
        oA[0][e] = 0.f; oA[1][e] = 0.f; olA[e] = 0.f;
        oB[0][e] = 0.f; oB[1][e] = 0.f; olB[e] = 0.f;
    }

    const int NT = 1024/64;   // 16 iterations; each covers 64 keys PER stream
    stage64(KpA, VpA, KsA[0], VsA[0], 0, w, l);
    stage64(KpB, VpB, KsB[0], VsB[0], 0, w, l);

    // exp + pa_sum + pack + PV + single ones-MFMA, one stream
#define SOFTPV(sc, Vsb, oacc, olacc)                                           \
    {                                                                          \
        _Pragma("unroll")                                                      \
        for (int q4 = 0; q4 < 2; ++q4)                                         \
            _Pragma("unroll")                                                  \
            for (int e = 0; e < 16; ++e)                                       \
                sc[q4][e] = __builtin_amdgcn_exp2f(sc[q4][e]);                 \
        float ss[8];                                                           \
        _Pragma("unroll")                                                      \
        for (int j = 0; j < 8; ++j)                                            \
            ss[j] = (sc[0][j] + sc[0][8+j]) + (sc[1][j] + sc[1][8+j]);         \
        __builtin_amdgcn_s_setprio(1);                                         \
        _Pragma("unroll")                                                      \
        for (int q4 = 0; q4 < 2; ++q4) {                                       \
            _Pragma("unroll")                                                  \
            for (int s2 = 0; s2 < 2; ++s2) {                                   \
                unsigned a0 = cvtpk(sc[q4][8*s2+0], sc[q4][8*s2+1]);           \
                unsigned a1 = cvtpk(sc[q4][8*s2+2], sc[q4][8*s2+3]);           \
                unsigned a2 = cvtpk(sc[q4][8*s2+4], sc[q4][8*s2+5]);           \
                unsigned a3 = cvtpk(sc[q4][8*s2+6], sc[q4][8*s2+7]);           \
                plswap(a0, a2); plswap(a1, a3);                                \
                u32x4 aw = {a0, a1, a2, a3};                                   \
                s16x8 paf = __builtin_bit_cast(s16x8, aw);                     \
                const int ks_ = 2*q4 + s2;                                     \
                _Pragma("unroll")                                              \
                for (int dt = 0; dt < 2; ++dt) {                               \
                    const int d_ = li + 32*dt;                                 \
                    s16x8 vf = *(const s16x8*)&Vsb[d_*64 + 8*((hi + 2*ks_) ^ (li & 7))]; \
                    oacc[dt] = MFMA32(paf, vf, oacc[dt]);                      \
                }                                                              \
            }                                                                  \
        }                                                                      \
        {                                                                      \
            unsigned a0 = cvtpk(ss[0], ss[1]);                                 \
            unsigned a1 = cvtpk(ss[2], ss[3]);                                 \
            unsigned a2 = cvtpk(ss[4], ss[5]);                                 \
            unsigned a3 = cvtpk(ss[6], ss[7]);                                 \
            plswap(a0, a2); plswap(a1, a3);                                    \
            u32x4 aw = {a0, a1, a2, a3};                                       \
            olacc = MFMA32(__builtin_bit_cast(s16x8, aw), ones, olacc);        \
        }                                                                      \
        __builtin_amdgcn_s_setprio(0);                                         \
    }

    #pragma unroll 1
    for (int kt = 0; kt < NT; ++kt) {
        const int cur = kt & 1;
        asm volatile("s_waitcnt vmcnt(0)" ::: "memory");   // own loads for kt
        __builtin_amdgcn_s_barrier();                      // everyone's landed;
                                                           // prev reads done
        if (kt + 1 < NT) {
            stage64(KpA, VpA, KsA[cur^1], VsA[cur^1], 64*(kt + 1), w, l);
            stage64(KpB, VpB, KsB[cur^1], VsB[cur^1], 64*(kt + 1), w, l);
        }

        // ---- QK^T both streams, 4 interleaved chains, zf-seeded ----
        f32x16 scA[2], scB[2];
        __builtin_amdgcn_s_setprio(1);
        {
            const int chk = 8*(hi ^ (li & 7));
            s16x8 ka0 = *(const s16x8*)&KsA[cur][(     li)*64 + chk];
            s16x8 ka1 = *(const s16x8*)&KsA[cur][(32 + li)*64 + chk];
            s16x8 kb0 = *(const s16x8*)&KsB[cur][(     li)*64 + chk];
            s16x8 kb1 = *(const s16x8*)&KsB[cur][(32 + li)*64 + chk];
            scA[0] = MFMA32(ka0, qf[0], zf);
            scA[1] = MFMA32(ka1, qf[0], zf);
            scB[0] = MFMA32(kb0, qf[0], zf);
            scB[1] = MFMA32(kb1, qf[0], zf);
        }
        #pragma unroll
        for (int kk = 1; kk < 4; ++kk) {
            const int chk = 8*((hi + 2*kk) ^ (li & 7));
            s16x8 ka0 = *(const s16x8*)&KsA[cur][(     li)*64 + chk];
            s16x8 ka1 = *(const s16x8*)&KsA[cur][(32 + li)*64 + chk];
            s16x8 kb0 = *(const s16x8*)&KsB[cur][(     li)*64 + chk];
            s16x8 kb1 = *(const s16x8*)&KsB[cur][(32 + li)*64 + chk];
            scA[0] = MFMA32(ka0, qf[kk], scA[0]);
            scA[1] = MFMA32(ka1, qf[kk], scA[1]);
            scB[0] = MFMA32(kb0, qf[kk], scB[0]);
            scB[1] = MFMA32(kb1, qf[kk], scB[1]);
        }
        __builtin_amdgcn_s_setprio(0);

        // ---- stream A softmax+PV (exp_B overlaps PV_A's MFMA drain) ----
        SOFTPV(scA, VsA[cur], oA, olA);
        SOFTPV(scB, VsB[cur], oB, olB);
    }
#undef SOFTPV

    // ---- epilogue: in-register combine of the two streams ------------------
    #pragma unroll
    for (int r = 0; r < 16; ++r) {
        const int qq = (r & 3) + 8*(r >> 2) + 4*hi;
        const int s  = qt*128 + w*32 + qq;
        const float inv = 1.0f / (olA[r] + olB[r]);
        #pragma unroll
        for (int dt = 0; dt < 2; ++dt)
            attnb[((size_t)b*S_ + s)*D_ + h*HD_ + li + 32*dt] =
                f2b((oA[dt][r] + oB[dt][r]) * inv);
    }
}

extern "C" void kernel_launch(void* const* d_in, const int* in_sizes, int n_in,
                              void* d_out, int out_size, void* d_ws, size_t ws_size,
                              hipStream_t stream)
{
    const float* x  = (const float*)d_in[0];
    const float* Wq = (const float*)d_in[1];
    const float* Wk = (const float*)d_in[2];
    const float* Wv = (const float*)d_in[3];
    const float* Wo = (const float*)d_in[4];
    float* out = (float*)d_out;

    char* p = (char*)d_ws;
    unsigned short* xb    = (unsigned short*)p; p += (size_t)B_*S_*D_*2;      // 8 MB
    unsigned short* wb    = (unsigned short*)p; p += (size_t)1536*1024*2;     // 3 MB
    unsigned short* wob   = (unsigned short*)p; p += (size_t)1024*1024*2;     // 2 MB
    unsigned short* qr    = (unsigned short*)p; p += (size_t)B_*H_*S_*HD_*2;  // 8 MB
    unsigned short* kr    = (unsigned short*)p; p += (size_t)B_*G_*S_*HD_*2;  // 2 MB
    unsigned short* vt    = (unsigned short*)p; p += (size_t)B_*G_*HD_*S_*2;  // 2 MB
    unsigned short* attnb = (unsigned short*)p; p += (size_t)B_*S_*D_*2;      // 8 MB
    float* cost = (float*)p; p += (size_t)S_*32*4;
    float* sint = (float*)p;

    prep_all<<<6720, 256, 0, stream>>>(x, Wq, Wk, Wv, Wo, xb, wb, wob, cost, sint);
    gemm_mfma<0><<<64*12, 256, 0, stream>>>(xb, wb, qr, kr, vt, nullptr, cost, sint, 12);
    flash_attn_mfma<<<B_*H_*(S_/128), 256, 0, stream>>>(qr, kr, vt, attnb);
    gemm_mfma<1><<<64*8, 256, 0, stream>>>(attnb, wob, nullptr, nullptr, nullptr, out, cost, sint, 8);
}